// Round 1
// 683.884 us; speedup vs baseline: 1.0373x; 1.0373x over previous
//
#include <hip/hip_runtime.h>

// Segment mean: x [N=1048576, D=128] fp32, B=16 contiguous segments given by
// lengths[16]. out [16,128] fp32 = per-segment column means.
//
// v2: phase 1 unrolls 4 rows per thread per iteration (4 independent float4
// loads batched under one vmcnt wait -> 4x memory-level parallelism per wave);
// phase 2 uses 256 threads (8 b-slots x 32 float4 cols) instead of 128
// latency-serialized scalar chains.

#define SEG_D 128
#define SEG_D4 32   // 128 floats = 32 float4
#define NSEG 16

__device__ __forceinline__ void acc4(float4& a, const float4 v) {
  a.x += v.x; a.y += v.y; a.z += v.z; a.w += v.w;
}

__global__ __launch_bounds__(256) void seg_partial_kernel(
    const float* __restrict__ x,
    const int* __restrict__ lengths,
    float* __restrict__ partial) {
  const int s  = blockIdx.y;
  const int bx = blockIdx.x;
  const int xb = gridDim.x;

  // Segment start offset and length from lengths[] (16 cached scalar reads).
  long long start = 0;
  int len = 0;
#pragma unroll
  for (int i = 0; i < NSEG; ++i) {
    const int l = lengths[i];
    if (i < s) start += l;
    if (i == s) len = l;
  }

  const int ro = threadIdx.x >> 5;   // row slot 0..7
  const int c  = threadIdx.x & 31;   // float4 column 0..31

  const float4* __restrict__ x4 = (const float4*)x;

  float4 a0 = make_float4(0.f, 0.f, 0.f, 0.f);
  float4 a1 = a0, a2 = a0, a3 = a0;

  // Block covers 32 consecutive rows per iteration: row = bx*32 + ro + 8*k,
  // k in {0..3}. Wave reads 2 contiguous rows per load instr (1 KiB).
  const long long step  = (long long)xb * 32;           // rows per grid sweep
  long long r = (long long)bx * 32 + ro;
  const float4* p = x4 + (start + r) * SEG_D4 + c;
  const long long pstep = step * SEG_D4;

  for (; r + 24 < len; r += step) {
    // 4 independent loads -> 4 outstanding vmem ops before the adds wait.
    const float4 v0 = p[0];
    const float4 v1 = p[8  * SEG_D4];
    const float4 v2 = p[16 * SEG_D4];
    const float4 v3 = p[24 * SEG_D4];
    acc4(a0, v0); acc4(a1, v1); acc4(a2, v2); acc4(a3, v3);
    p += pstep;
  }
  // Tail: at most one partial group (r+24 >= len here).
  if (r < len)      acc4(a0, p[0]);
  if (r + 8 < len)  acc4(a1, p[8  * SEG_D4]);
  if (r + 16 < len) acc4(a2, p[16 * SEG_D4]);

  acc4(a0, a1); acc4(a2, a3); acc4(a0, a2);

  // 8-way reduction across row slots via LDS.
  __shared__ float4 red[256];
  red[threadIdx.x] = a0;
  __syncthreads();
  if (threadIdx.x < 32) {
    float4 sum = red[threadIdx.x];
#pragma unroll
    for (int i = 1; i < 8; ++i) acc4(sum, red[threadIdx.x + i * 32]);
    ((float4*)partial)[((long long)s * xb + bx) * SEG_D4 + threadIdx.x] = sum;
  }
}

__global__ __launch_bounds__(256) void seg_finish_kernel(
    const float* __restrict__ partial,
    const int* __restrict__ lengths,
    float* __restrict__ out,
    int xb) {
  const int s  = blockIdx.x;
  const int bo = threadIdx.x >> 5;   // partial-block slot 0..7
  const int c  = threadIdx.x & 31;   // float4 column 0..31

  const float4* p4 = (const float4*)partial + (long long)s * xb * SEG_D4 + c;
  float4 sum = make_float4(0.f, 0.f, 0.f, 0.f);
  for (int b = bo; b < xb; b += 8) {
    acc4(sum, p4[(long long)b * SEG_D4]);
  }

  __shared__ float4 red[256];
  red[threadIdx.x] = sum;
  __syncthreads();
  if (threadIdx.x < 32) {
    float4 t = red[threadIdx.x];
#pragma unroll
    for (int i = 1; i < 8; ++i) acc4(t, red[threadIdx.x + i * 32]);
    const float inv = 1.0f / (float)lengths[s];
    t.x *= inv; t.y *= inv; t.z *= inv; t.w *= inv;
    ((float4*)out)[s * SEG_D4 + threadIdx.x] = t;
  }
}

extern "C" void kernel_launch(void* const* d_in, const int* in_sizes, int n_in,
                              void* d_out, int out_size, void* d_ws, size_t ws_size,
                              hipStream_t stream) {
  const float* x       = (const float*)d_in[0];
  // d_in[1] = segment_ids (int32) — unused; segments are contiguous, lengths suffice.
  const int*   lengths = (const int*)d_in[2];
  float*       out     = (float*)d_out;
  float*       partial = (float*)d_ws;

  // XB partial blocks per segment; cap by workspace (needs NSEG*XB*D*4 bytes).
  int xb = 128;
  const size_t need_per_xb = (size_t)NSEG * SEG_D * sizeof(float);
  while (xb > 1 && (size_t)xb * need_per_xb > ws_size) xb >>= 1;

  dim3 grid1(xb, NSEG);
  seg_partial_kernel<<<grid1, 256, 0, stream>>>(x, lengths, partial);
  seg_finish_kernel<<<NSEG, SEG_D * 2, 0, stream>>>(partial, lengths, out, xb);
}

// Round 4
// 680.137 us; speedup vs baseline: 1.0430x; 1.0055x over previous
//
#include <hip/hip_runtime.h>

// Segment mean: x [N, D=128] fp32, B=16 contiguous segments (lengths[16]).
// out [16,128] fp32 = per-segment column means.
//
// v3c: load-balanced phase 1 — every block reduces an identical CROWS-row chunk
// of the GLOBAL row space (x is contiguous across segments). Min segment length
// (~21K rows) >> CROWS, so a chunk crosses at most ONE segment boundary: each
// block emits two partials (run A = rows before the boundary, run B = after;
// B is zeros when no boundary). Phase 2 derives entry->segment ownership from
// prefix sums of lengths — no tags, no atomics, deterministic.
//
// v3c fix: in_sizes units are ambiguous (elements vs bytes). lengths is
// int32[16], so in_sizes[2]==16 => elements, ==64 => bytes. Derive nrows
// robustly from that discriminator. (v3b assumed bytes; under the elements
// convention it processed N/4 rows and read poisoned workspace.)

#define SEG_D   128
#define SEG_D4  32    // 128 floats = 32 float4
#define NSEG    16
#define CROWS   512   // rows per chunk; chunk = 256 KiB

__device__ __forceinline__ void acc4(float4& a, const float4 v) {
  a.x += v.x; a.y += v.y; a.z += v.z; a.w += v.w;
}

__global__ __launch_bounds__(256) void seg_partial_kernel(
    const float4* __restrict__ x4,
    const int* __restrict__ lengths,
    float4* __restrict__ partial,   // [T][2][SEG_D4]
    int nrows) {
  const int b = blockIdx.x;
  const int t = threadIdx.x;
  const long long row_lo = (long long)b * CROWS;
  long long row_hi = row_lo + CROWS;
  if (row_hi > nrows) row_hi = nrows;

  // Find end row of the segment containing row_lo.
  long long pre = 0, endA = 0;
  for (int i = 0; i < NSEG; ++i) {
    const long long l = lengths[i];
    if (pre + l > row_lo) { endA = pre + l; break; }
    pre += l;
  }
  const long long split = endA < row_hi ? endA : row_hi;

  const float4* __restrict__ base = x4 + row_lo * SEG_D4;
  const int nf  = (int)((row_hi - row_lo) * SEG_D4);   // <= CROWS*32 = 16384
  const int sp4 = (int)((split - row_lo) * SEG_D4);

  float4 a0 = make_float4(0.f, 0.f, 0.f, 0.f);
  float4 a1 = a0, a2 = a0, a3 = a0;           // run A accumulators
  float4 b0 = a0, b1 = a0, b2 = a0, b3 = a0;  // run B accumulators

  // 4 independent 1 KiB wave-loads in flight per iteration; thread's float4
  // column (t & 31) is invariant (strides are multiples of 32).
  int i = t;
  for (; i + 768 < nf; i += 1024) {
    const float4 v0 = base[i];
    const float4 v1 = base[i + 256];
    const float4 v2 = base[i + 512];
    const float4 v3 = base[i + 768];
    if (i       < sp4) acc4(a0, v0); else acc4(b0, v0);
    if (i + 256 < sp4) acc4(a1, v1); else acc4(b1, v1);
    if (i + 512 < sp4) acc4(a2, v2); else acc4(b2, v2);
    if (i + 768 < sp4) acc4(a3, v3); else acc4(b3, v3);
  }
  for (; i < nf; i += 256) {
    const float4 v = base[i];
    if (i < sp4) acc4(a0, v); else acc4(b0, v);
  }
  acc4(a0, a1); acc4(a2, a3); acc4(a0, a2);
  acc4(b0, b1); acc4(b2, b3); acc4(b0, b2);

  // Reduce 8 row-slots per column, for both runs.
  __shared__ float4 red[2][256];
  red[0][t] = a0;
  red[1][t] = b0;
  __syncthreads();
  if (t < 64) {
    const int which = t >> 5;   // 0 = run A, 1 = run B
    const int c     = t & 31;
    float4 sum = red[which][c];
#pragma unroll
    for (int k = 1; k < 8; ++k) acc4(sum, red[which][c + k * 32]);
    partial[((long long)b * 2 + which) * SEG_D4 + c] = sum;
  }
}

__global__ __launch_bounds__(256) void seg_finish_kernel(
    const float4* __restrict__ partial,
    const int* __restrict__ lengths,
    float4* __restrict__ out) {
  const int s    = blockIdx.x;
  const int slot = threadIdx.x >> 5;   // 0..7
  const int c    = threadIdx.x & 31;   // float4 column

  long long pre = 0;
  for (int i = 0; i < s; ++i) pre += lengths[i];
  const long long len = lengths[s];
  const long long end = pre + len;

  // Chunks whose A-run lies in segment s: pre <= b*CROWS < end.
  const int bA_lo = (int)((pre + CROWS - 1) / CROWS);
  const int bA_hi = (int)((end - 1) / CROWS);

  float4 sum = make_float4(0.f, 0.f, 0.f, 0.f);
  for (int b = bA_lo + slot; b <= bA_hi; b += 8)
    acc4(sum, partial[((long long)b * 2) * SEG_D4 + c]);

  // The straddling chunk (if the boundary is interior to it) holds s's head
  // rows in its B-slot. Added once, by slot 0.
  if (slot == 0 && (pre % CROWS) != 0) {
    const int bx = (int)(pre / CROWS);
    acc4(sum, partial[((long long)bx * 2 + 1) * SEG_D4 + c]);
  }

  __shared__ float4 red[256];
  red[threadIdx.x] = sum;
  __syncthreads();
  if (threadIdx.x < 32) {
    float4 tt = red[threadIdx.x];
#pragma unroll
    for (int k = 1; k < 8; ++k) acc4(tt, red[threadIdx.x + k * 32]);
    const float inv = 1.0f / (float)len;
    tt.x *= inv; tt.y *= inv; tt.z *= inv; tt.w *= inv;
    out[s * SEG_D4 + threadIdx.x] = tt;
  }
}

extern "C" void kernel_launch(void* const* d_in, const int* in_sizes, int n_in,
                              void* d_out, int out_size, void* d_ws, size_t ws_size,
                              hipStream_t stream) {
  const float* x       = (const float*)d_in[0];
  // d_in[1] = segment_ids (int32) — unused; segments contiguous, lengths suffice.
  const int*   lengths = (const int*)d_in[2];
  float*       out     = (float*)d_out;

  // lengths is int32[16]: in_sizes[2]==16 -> element counts, ==64 -> bytes.
  const bool sizes_in_bytes = (in_sizes[2] >= 64);
  const long long denom = sizes_in_bytes ? (long long)SEG_D * 4 : (long long)SEG_D;
  const int nrows = (int)((long long)in_sizes[0] / denom);
  const int T     = (nrows + CROWS - 1) / CROWS;   // 2048 for N=1M

  float4* partial = (float4*)d_ws;   // needs T*2*512 B = 2 MiB << ws_size

  seg_partial_kernel<<<T, 256, 0, stream>>>(
      (const float4*)x, lengths, partial, nrows);
  seg_finish_kernel<<<NSEG, 256, 0, stream>>>(
      partial, lengths, (float4*)out);
}